// Round 1
// baseline (253.423 us; speedup 1.0000x reference)
//
#include <hip/hip_runtime.h>
#include <math.h>

#define N 4096
#define C 512
#define EMB 38
#define XSTR 40      // padded row stride for embedded features
#define HEADS 4
#define HID 64
#define F1 256       // HEADS*HID
#define MAXN 128     // max neighbors per row (p=0.01 -> mean 41, >13 sigma headroom)
#define R2 8         // rows per block in gemm2

__device__ __forceinline__ float wr_sum(float v) {
#pragma unroll
    for (int o = 32; o > 0; o >>= 1) v += __shfl_xor(v, o);
    return v;
}
__device__ __forceinline__ float wr_max(float v) {
#pragma unroll
    for (int o = 32; o > 0; o >>= 1) v = fmaxf(v, __shfl_xor(v, o));
    return v;
}

// ---------------- feature embedding: [N,8] -> [N,38] (stride 40) ----------------
__global__ void k_embed(const float* __restrict__ nf, float* __restrict__ x38) {
    int n = blockIdx.x * blockDim.x + threadIdx.x;
    if (n >= N) return;
    const float* f = nf + n * 8;
    float* r = x38 + n * XSTR;
    int nt = (int)f[0]; nt = min(max(nt, 0), 5);
#pragma unroll
    for (int t = 0; t < 6; ++t) r[t] = (t == nt) ? 1.f : 0.f;
    r[6] = log1pf(f[1]);
    float divs[4];
#pragma unroll
    for (int m = 0; m < 4; ++m) divs[m] = expf((2.f * m) * (-logf(10000.f) / 8.f));
    float v3[3]; v3[0] = f[2]; v3[1] = f[3]; v3[2] = f[4] * 100.f;
#pragma unroll
    for (int s = 0; s < 3; ++s) {
#pragma unroll
        for (int m = 0; m < 4; ++m) {
            float sc = v3[s] * divs[m];
            r[7 + s * 8 + 2 * m]     = sinf(sc);
            r[7 + s * 8 + 2 * m + 1] = cosf(sc);
        }
    }
    int role = (int)f[5]; role = min(max(role, 0), 4);
#pragma unroll
    for (int t = 0; t < 5; ++t) r[31 + t] = (t == role) ? 1.f : 0.f;
    r[36] = f[6];
    r[37] = f[7];
}

// ---------------- build CSR neighbor lists from dense adj (read adj ONCE) ----------------
__global__ void k_build(const float* __restrict__ adj, int* __restrict__ cnt, int* __restrict__ idx) {
    int i = blockIdx.x;
    __shared__ int c;
    if (threadIdx.x == 0) c = 0;
    __syncthreads();
    const float* row = adj + (size_t)i * N;
    for (int j = threadIdx.x; j < N; j += blockDim.x) {
        if (row[j] > 0.f) {
            int p = atomicAdd(&c, 1);
            if (p < MAXN) idx[i * MAXN + p] = j;
        }
    }
    __syncthreads();
    if (threadIdx.x == 0) cnt[i] = min(c, MAXN);
}

// ---------------- GEMM1 [N,38]@[38,256] + fused src/dst attention dots ----------------
__global__ void k_gemm1(const float* __restrict__ x38, const float* __restrict__ W1,
                        const float* __restrict__ asrc, const float* __restrict__ adst,
                        float* __restrict__ h1, float* __restrict__ s1, float* __restrict__ d1) {
    int n = blockIdx.x, tid = threadIdx.x;
    __shared__ float xs[EMB];
    if (tid < EMB) xs[tid] = x38[n * XSTR + tid];
    __syncthreads();
    float acc = 0.f;
#pragma unroll
    for (int k = 0; k < EMB; ++k) acc += xs[k] * W1[k * F1 + tid];
    h1[(size_t)n * F1 + tid] = acc;
    int h = tid >> 6, lane = tid & 63;
    float ss = wr_sum(acc * asrc[tid]);
    float dd = wr_sum(acc * adst[tid]);
    if (lane == 0) { s1[n * HEADS + h] = ss; d1[n * HEADS + h] = dd; }
}

// ---------------- GEMM2 [N,256]@[256,256] + fused src/dst attention dots ----------------
__global__ void k_gemm2(const float* __restrict__ x1, const float* __restrict__ W2,
                        const float* __restrict__ asrc, const float* __restrict__ adst,
                        float* __restrict__ h2, float* __restrict__ s2, float* __restrict__ d2) {
    int n0 = blockIdx.x * R2, tid = threadIdx.x;
    __shared__ float xs[R2][F1];
#pragma unroll
    for (int r = 0; r < R2; ++r) xs[r][tid] = x1[(size_t)(n0 + r) * F1 + tid];
    __syncthreads();
    float acc[R2];
#pragma unroll
    for (int r = 0; r < R2; ++r) acc[r] = 0.f;
#pragma unroll 4
    for (int k = 0; k < F1; ++k) {
        float wv = W2[k * F1 + tid];
#pragma unroll
        for (int r = 0; r < R2; ++r) acc[r] += xs[r][k] * wv;
    }
    int h = tid >> 6, lane = tid & 63;
#pragma unroll
    for (int r = 0; r < R2; ++r) {
        h2[(size_t)(n0 + r) * F1 + tid] = acc[r];
        float ss = wr_sum(acc[r] * asrc[tid]);
        float dd = wr_sum(acc[r] * adst[tid]);
        if (lane == 0) { s2[(n0 + r) * HEADS + h] = ss; d2[(n0 + r) * HEADS + h] = dd; }
    }
}

// ---------------- GAT aggregation layer 1 (concat heads) + LN(256) + ELU ----------------
__global__ void k_agg1(const float* __restrict__ h1, const float* __restrict__ s1,
                       const float* __restrict__ d1, const int* __restrict__ cnt,
                       const int* __restrict__ idx, const float* __restrict__ g,
                       const float* __restrict__ b, float* __restrict__ xo) {
    int i = blockIdx.x, tid = threadIdx.x;
    int h = tid >> 6, lane = tid & 63;
    __shared__ int nbrs[MAXN];
    __shared__ float w[HEADS][MAXN];
    __shared__ float red[HEADS];
    int c = cnt[i];
    if (tid < c) nbrs[tid] = idx[i * MAXN + tid];
    __syncthreads();
    float si = s1[i * HEADS + h];
    float m = -INFINITY;
    for (int jj = lane; jj < c; jj += 64) {
        float e = si + d1[nbrs[jj] * HEADS + h];
        e = e > 0.f ? e : 0.2f * e;     // leaky_relu(0.2)
        w[h][jj] = e;
        m = fmaxf(m, e);
    }
    m = wr_max(m);
    float l = 0.f;
    for (int jj = lane; jj < c; jj += 64) {
        float t = expf(w[h][jj] - m);
        w[h][jj] = t;
        l += t;
    }
    l = wr_sum(l);
    __syncthreads();
    float acc = 0.f;
    for (int jj = 0; jj < c; ++jj)
        acc += w[h][jj] * h1[(size_t)nbrs[jj] * F1 + tid];   // tid = h*64+d
    acc /= l;
    // LayerNorm over 256 + ELU (tid indexes the concat layout directly)
    float s = wr_sum(acc);
    if (lane == 0) red[h] = s;
    __syncthreads();
    float mu = (red[0] + red[1] + red[2] + red[3]) * (1.f / F1);
    float dv = acc - mu;
    float s2 = wr_sum(dv * dv);
    __syncthreads();
    if (lane == 0) red[h] = s2;
    __syncthreads();
    float var = (red[0] + red[1] + red[2] + red[3]) * (1.f / F1);
    float y = dv * rsqrtf(var + 1e-5f) * g[tid] + b[tid];
    xo[(size_t)i * F1 + tid] = y > 0.f ? y : expm1f(y);
}

// ---------------- GAT aggregation layer 2 (mean heads) + LN(64) + ELU ----------------
__global__ void k_agg2(const float* __restrict__ h2, const float* __restrict__ s2,
                       const float* __restrict__ d2, const int* __restrict__ cnt,
                       const int* __restrict__ idx, const float* __restrict__ g,
                       const float* __restrict__ b, float* __restrict__ xo) {
    int i = blockIdx.x, tid = threadIdx.x;
    int h = tid >> 6, lane = tid & 63;
    __shared__ int nbrs[MAXN];
    __shared__ float w[HEADS][MAXN];
    __shared__ float vals[F1];
    int c = cnt[i];
    if (tid < c) nbrs[tid] = idx[i * MAXN + tid];
    __syncthreads();
    float si = s2[i * HEADS + h];
    float m = -INFINITY;
    for (int jj = lane; jj < c; jj += 64) {
        float e = si + d2[nbrs[jj] * HEADS + h];
        e = e > 0.f ? e : 0.2f * e;
        w[h][jj] = e;
        m = fmaxf(m, e);
    }
    m = wr_max(m);
    float l = 0.f;
    for (int jj = lane; jj < c; jj += 64) {
        float t = expf(w[h][jj] - m);
        w[h][jj] = t;
        l += t;
    }
    l = wr_sum(l);
    __syncthreads();
    float acc = 0.f;
    for (int jj = 0; jj < c; ++jj)
        acc += w[h][jj] * h2[(size_t)nbrs[jj] * F1 + tid];
    vals[tid] = acc / l;
    __syncthreads();
    if (tid < HID) {
        float mv = (vals[tid] + vals[tid + 64] + vals[tid + 128] + vals[tid + 192]) * 0.25f;
        float mu = wr_sum(mv) * (1.f / HID);
        float dv = mv - mu;
        float var = wr_sum(dv * dv) * (1.f / HID);
        float y = dv * rsqrtf(var + 1e-5f) * g[tid] + b[tid];
        xo[i * HID + tid] = y > 0.f ? y : expm1f(y);
    }
}

// ---------------- clause pooling: sparse [C,N] @ [N,64], ballot-compacted ----------------
__global__ void k_pool(const float* __restrict__ pm, const float* __restrict__ x2,
                       float* __restrict__ ce) {
    int c = blockIdx.x, d = threadIdx.x;
    float acc = 0.f;
    for (int base = 0; base < N; base += 64) {
        float p = pm[(size_t)c * N + base + d];
        unsigned long long msk = __ballot(p != 0.f);
        while (msk) {
            int bpos = __ffsll((unsigned long long)msk) - 1;
            msk &= msk - 1;
            float pj = __shfl(p, bpos);
            acc += pj * x2[(size_t)(base + bpos) * HID + d];
        }
    }
    ce[c * HID + d] = acc;
}

// ---------------- scorer: relu(ce@Ws+bs)@Wo+bo -> [C] ----------------
__global__ void k_score(const float* __restrict__ ce, const float* __restrict__ Ws,
                        const float* __restrict__ bs, const float* __restrict__ Wo,
                        const float* __restrict__ bo, float* __restrict__ out) {
    int c = blockIdx.x, d = threadIdx.x;
    float hd = bs[d];
#pragma unroll 4
    for (int k = 0; k < HID; ++k) hd += ce[c * HID + k] * Ws[k * HID + d];
    hd = fmaxf(hd, 0.f);
    float v = wr_sum(hd * Wo[d]);
    if (d == 0) out[c] = v + bo[0];
}

extern "C" void kernel_launch(void* const* d_in, const int* in_sizes, int n_in,
                              void* d_out, int out_size, void* d_ws, size_t ws_size,
                              hipStream_t stream) {
    const float* nf  = (const float*)d_in[0];
    const float* adj = (const float*)d_in[1];
    const float* pm  = (const float*)d_in[2];
    const float* W1  = (const float*)d_in[3];
    const float* as1 = (const float*)d_in[4];
    const float* ad1 = (const float*)d_in[5];
    const float* g1  = (const float*)d_in[6];
    const float* b1  = (const float*)d_in[7];
    const float* W2  = (const float*)d_in[8];
    const float* as2 = (const float*)d_in[9];
    const float* ad2 = (const float*)d_in[10];
    const float* g2  = (const float*)d_in[11];
    const float* b2  = (const float*)d_in[12];
    const float* Ws  = (const float*)d_in[13];
    const float* bs  = (const float*)d_in[14];
    const float* Wo  = (const float*)d_in[15];
    const float* bo  = (const float*)d_in[16];
    float* out = (float*)d_out;

    float* p = (float*)d_ws;
    float* x38 = p; p += (size_t)N * XSTR;
    float* h1  = p; p += (size_t)N * F1;
    float* s1  = p; p += (size_t)N * HEADS;
    float* d1  = p; p += (size_t)N * HEADS;
    float* x1  = p; p += (size_t)N * F1;
    float* h2  = p; p += (size_t)N * F1;
    float* s2  = p; p += (size_t)N * HEADS;
    float* d2  = p; p += (size_t)N * HEADS;
    float* x2  = p; p += (size_t)N * HID;
    float* ce  = p; p += (size_t)C * HID;
    int* cnt = (int*)p;
    int* idx = cnt + N;

    k_embed<<<(N + 255) / 256, 256, 0, stream>>>(nf, x38);
    k_build<<<N, 256, 0, stream>>>(adj, cnt, idx);
    k_gemm1<<<N, 256, 0, stream>>>(x38, W1, as1, ad1, h1, s1, d1);
    k_agg1<<<N, 256, 0, stream>>>(h1, s1, d1, cnt, idx, g1, b1, x1);
    k_gemm2<<<N / R2, 256, 0, stream>>>(x1, W2, as2, ad2, h2, s2, d2);
    k_agg2<<<N, 256, 0, stream>>>(h2, s2, d2, cnt, idx, g2, b2, x2);
    k_pool<<<C, 64, 0, stream>>>(pm, x2, ce);
    k_score<<<C, 64, 0, stream>>>(ce, Ws, bs, Wo, bo, out);
}

// Round 2
// 202.631 us; speedup vs baseline: 1.2507x; 1.2507x over previous
//
#include <hip/hip_runtime.h>
#include <math.h>

#define N 4096
#define C 512
#define EMB 38
#define HEADS 4
#define HID 64
#define F1 256       // HEADS*HID
#define MAXN 128     // max neighbors per row (p=0.01 -> mean 41, >13 sigma headroom)
#define R2 8         // rows per block in gemms

__device__ __forceinline__ float wr_sum(float v) {
#pragma unroll
    for (int o = 32; o > 0; o >>= 1) v += __shfl_xor(v, o);
    return v;
}
__device__ __forceinline__ float wr_max(float v) {
#pragma unroll
    for (int o = 32; o > 0; o >>= 1) v = fmaxf(v, __shfl_xor(v, o));
    return v;
}

// ---------------- build CSR neighbor lists from dense adj (read adj ONCE, float4) ----------------
__global__ __launch_bounds__(256) void k_build(const float* __restrict__ adj,
                                               int* __restrict__ cnt, int* __restrict__ idx) {
    int i = blockIdx.x;
    __shared__ int c;
    if (threadIdx.x == 0) c = 0;
    __syncthreads();
    const float4* row = (const float4*)(adj + (size_t)i * N);
    for (int v = threadIdx.x; v < N / 4; v += blockDim.x) {
        float4 a = row[v];
        if (a.x > 0.f) { int p = atomicAdd(&c, 1); if (p < MAXN) idx[i * MAXN + p] = 4 * v + 0; }
        if (a.y > 0.f) { int p = atomicAdd(&c, 1); if (p < MAXN) idx[i * MAXN + p] = 4 * v + 1; }
        if (a.z > 0.f) { int p = atomicAdd(&c, 1); if (p < MAXN) idx[i * MAXN + p] = 4 * v + 2; }
        if (a.w > 0.f) { int p = atomicAdd(&c, 1); if (p < MAXN) idx[i * MAXN + p] = 4 * v + 3; }
    }
    __syncthreads();
    if (threadIdx.x == 0) cnt[i] = min(c, MAXN);
}

// ---------------- fused embed + GEMM1 [8 nodes/block: 38->256] + attention dots ----------------
__global__ __launch_bounds__(256) void k_gemm1(const float* __restrict__ nf, const float* __restrict__ W1,
                                               const float* __restrict__ asrc, const float* __restrict__ adst,
                                               float* __restrict__ h1, float* __restrict__ s1, float* __restrict__ d1) {
    int n0 = blockIdx.x * R2, tid = threadIdx.x;
    __shared__ float fs[R2][8];
    __shared__ float xs[R2][EMB + 2];
    if (tid < R2 * 8) fs[tid >> 3][tid & 7] = nf[(size_t)(n0 + (tid >> 3)) * 8 + (tid & 7)];
    __syncthreads();
    // each thread computes one (row, feature) of the embedding
    {
        int r = tid & 7;
        int t = tid >> 3;               // 0..31
        const float* f = fs[r];
        for (int pass = 0; pass < 2; ++pass, t += 32) {
            if (t >= EMB) break;
            float val;
            if (t < 6) { int nt = min(max((int)f[0], 0), 5); val = (t == nt) ? 1.f : 0.f; }
            else if (t == 6) val = log1pf(f[1]);
            else if (t < 31) {
                int q = (t - 7) & 7, s = (t - 7) >> 3, m = q >> 1;
                float base = (s == 0) ? f[2] : (s == 1) ? f[3] : f[4] * 100.f;
                float div = expf((2.f * m) * (-logf(10000.f) / 8.f));
                float sc = base * div;
                val = (q & 1) ? cosf(sc) : sinf(sc);
            }
            else if (t < 36) { int role = min(max((int)f[5], 0), 4); val = (t - 31 == role) ? 1.f : 0.f; }
            else val = (t == 36) ? f[6] : f[7];
            xs[r][t] = val;
        }
    }
    __syncthreads();
    float acc[R2];
#pragma unroll
    for (int r = 0; r < R2; ++r) acc[r] = 0.f;
#pragma unroll
    for (int k = 0; k < EMB; ++k) {
        float wv = W1[k * F1 + tid];
#pragma unroll
        for (int r = 0; r < R2; ++r) acc[r] = fmaf(xs[r][k], wv, acc[r]);
    }
    int h = tid >> 6, lane = tid & 63;
    float av = asrc[tid], dv = adst[tid];
#pragma unroll
    for (int r = 0; r < R2; ++r) {
        h1[(size_t)(n0 + r) * F1 + tid] = acc[r];
        float ss = wr_sum(acc[r] * av);
        float dd = wr_sum(acc[r] * dv);
        if (lane == 0) { s1[(n0 + r) * HEADS + h] = ss; d1[(n0 + r) * HEADS + h] = dd; }
    }
}

// ---------------- GEMM2 [N,256]@[256,256] + fused attention dots (float4 LDS) ----------------
__global__ __launch_bounds__(256) void k_gemm2(const float* __restrict__ x1, const float* __restrict__ W2,
                                               const float* __restrict__ asrc, const float* __restrict__ adst,
                                               float* __restrict__ h2, float* __restrict__ s2, float* __restrict__ d2) {
    int n0 = blockIdx.x * R2, tid = threadIdx.x;
    __shared__ float4 xs4[R2][F1 / 4];
    {
        int r = tid >> 5, kk = tid & 31;
        const float4* x1v = (const float4*)x1;
        xs4[r][kk]      = x1v[(size_t)(n0 + r) * 64 + kk];
        xs4[r][kk + 32] = x1v[(size_t)(n0 + r) * 64 + kk + 32];
    }
    __syncthreads();
    float acc[R2];
#pragma unroll
    for (int r = 0; r < R2; ++r) acc[r] = 0.f;
    for (int kk = 0; kk < F1 / 4; ++kk) {
        float w0 = W2[(4 * kk + 0) * F1 + tid];
        float w1 = W2[(4 * kk + 1) * F1 + tid];
        float w2 = W2[(4 * kk + 2) * F1 + tid];
        float w3 = W2[(4 * kk + 3) * F1 + tid];
#pragma unroll
        for (int r = 0; r < R2; ++r) {
            float4 x = xs4[r][kk];
            acc[r] = fmaf(x.x, w0, fmaf(x.y, w1, fmaf(x.z, w2, fmaf(x.w, w3, acc[r]))));
        }
    }
    int h = tid >> 6, lane = tid & 63;
    float av = asrc[tid], dv = adst[tid];
#pragma unroll
    for (int r = 0; r < R2; ++r) {
        h2[(size_t)(n0 + r) * F1 + tid] = acc[r];
        float ss = wr_sum(acc[r] * av);
        float dd = wr_sum(acc[r] * dv);
        if (lane == 0) { s2[(n0 + r) * HEADS + h] = ss; d2[(n0 + r) * HEADS + h] = dd; }
    }
}

// ---------------- GAT aggregation layer 1 (concat heads) + LN(256) + ELU ----------------
__global__ __launch_bounds__(256) void k_agg1(const float* __restrict__ h1, const float* __restrict__ s1,
                                              const float* __restrict__ d1, const int* __restrict__ cnt,
                                              const int* __restrict__ idx, const float* __restrict__ g,
                                              const float* __restrict__ b, float* __restrict__ xo) {
    int i = blockIdx.x, tid = threadIdx.x;
    int h = tid >> 6, lane = tid & 63;
    __shared__ int nbrs[MAXN];
    __shared__ float w[HEADS][MAXN];
    __shared__ float red[HEADS];
    int c = cnt[i];
    int c8 = (c + 7) & ~7;
    if (tid < c) nbrs[tid] = idx[i * MAXN + tid];
    if (tid >= c && tid < c8) {
        nbrs[tid] = i;
        w[0][tid] = 0.f; w[1][tid] = 0.f; w[2][tid] = 0.f; w[3][tid] = 0.f;
    }
    __syncthreads();
    float si = s1[i * HEADS + h];
    float m = -INFINITY;
    for (int jj = lane; jj < c; jj += 64) {
        float e = si + d1[nbrs[jj] * HEADS + h];
        e = e > 0.f ? e : 0.2f * e;     // leaky_relu(0.2)
        w[h][jj] = e;
        m = fmaxf(m, e);
    }
    m = wr_max(m);
    float l = 0.f;
    for (int jj = lane; jj < c; jj += 64) {
        float t = expf(w[h][jj] - m);
        w[h][jj] = t;
        l += t;
    }
    l = wr_sum(l);
    float acc0 = 0.f, acc1 = 0.f;
    for (int jj = 0; jj < c8; jj += 8) {
        int n0 = nbrs[jj], n1 = nbrs[jj + 1], n2 = nbrs[jj + 2], n3 = nbrs[jj + 3];
        int n4 = nbrs[jj + 4], n5 = nbrs[jj + 5], n6 = nbrs[jj + 6], n7 = nbrs[jj + 7];
        float w0 = w[h][jj], w1 = w[h][jj + 1], w2 = w[h][jj + 2], w3 = w[h][jj + 3];
        float w4 = w[h][jj + 4], w5 = w[h][jj + 5], w6 = w[h][jj + 6], w7 = w[h][jj + 7];
        float v0 = h1[(size_t)n0 * F1 + tid], v1 = h1[(size_t)n1 * F1 + tid];
        float v2 = h1[(size_t)n2 * F1 + tid], v3 = h1[(size_t)n3 * F1 + tid];
        float v4 = h1[(size_t)n4 * F1 + tid], v5 = h1[(size_t)n5 * F1 + tid];
        float v6 = h1[(size_t)n6 * F1 + tid], v7 = h1[(size_t)n7 * F1 + tid];
        acc0 = fmaf(w0, v0, fmaf(w1, v1, fmaf(w2, v2, fmaf(w3, v3, acc0))));
        acc1 = fmaf(w4, v4, fmaf(w5, v5, fmaf(w6, v6, fmaf(w7, v7, acc1))));
    }
    float acc = (acc0 + acc1) / l;
    // LayerNorm over 256 + ELU (tid indexes the concat layout directly)
    float s = wr_sum(acc);
    if (lane == 0) red[h] = s;
    __syncthreads();
    float mu = (red[0] + red[1] + red[2] + red[3]) * (1.f / F1);
    float dv = acc - mu;
    float s2 = wr_sum(dv * dv);
    __syncthreads();
    if (lane == 0) red[h] = s2;
    __syncthreads();
    float var = (red[0] + red[1] + red[2] + red[3]) * (1.f / F1);
    float y = dv * rsqrtf(var + 1e-5f) * g[tid] + b[tid];
    xo[(size_t)i * F1 + tid] = y > 0.f ? y : expm1f(y);
}

// ---------------- GAT aggregation layer 2 (mean heads) + LN(64) + ELU ----------------
__global__ __launch_bounds__(256) void k_agg2(const float* __restrict__ h2, const float* __restrict__ s2,
                                              const float* __restrict__ d2, const int* __restrict__ cnt,
                                              const int* __restrict__ idx, const float* __restrict__ g,
                                              const float* __restrict__ b, float* __restrict__ xo) {
    int i = blockIdx.x, tid = threadIdx.x;
    int h = tid >> 6, lane = tid & 63;
    __shared__ int nbrs[MAXN];
    __shared__ float w[HEADS][MAXN];
    __shared__ float vals[F1];
    int c = cnt[i];
    int c8 = (c + 7) & ~7;
    if (tid < c) nbrs[tid] = idx[i * MAXN + tid];
    if (tid >= c && tid < c8) {
        nbrs[tid] = i;
        w[0][tid] = 0.f; w[1][tid] = 0.f; w[2][tid] = 0.f; w[3][tid] = 0.f;
    }
    __syncthreads();
    float si = s2[i * HEADS + h];
    float m = -INFINITY;
    for (int jj = lane; jj < c; jj += 64) {
        float e = si + d2[nbrs[jj] * HEADS + h];
        e = e > 0.f ? e : 0.2f * e;
        w[h][jj] = e;
        m = fmaxf(m, e);
    }
    m = wr_max(m);
    float l = 0.f;
    for (int jj = lane; jj < c; jj += 64) {
        float t = expf(w[h][jj] - m);
        w[h][jj] = t;
        l += t;
    }
    l = wr_sum(l);
    float acc0 = 0.f, acc1 = 0.f;
    for (int jj = 0; jj < c8; jj += 8) {
        int n0 = nbrs[jj], n1 = nbrs[jj + 1], n2 = nbrs[jj + 2], n3 = nbrs[jj + 3];
        int n4 = nbrs[jj + 4], n5 = nbrs[jj + 5], n6 = nbrs[jj + 6], n7 = nbrs[jj + 7];
        float w0 = w[h][jj], w1 = w[h][jj + 1], w2 = w[h][jj + 2], w3 = w[h][jj + 3];
        float w4 = w[h][jj + 4], w5 = w[h][jj + 5], w6 = w[h][jj + 6], w7 = w[h][jj + 7];
        float v0 = h2[(size_t)n0 * F1 + tid], v1 = h2[(size_t)n1 * F1 + tid];
        float v2 = h2[(size_t)n2 * F1 + tid], v3 = h2[(size_t)n3 * F1 + tid];
        float v4 = h2[(size_t)n4 * F1 + tid], v5 = h2[(size_t)n5 * F1 + tid];
        float v6 = h2[(size_t)n6 * F1 + tid], v7 = h2[(size_t)n7 * F1 + tid];
        acc0 = fmaf(w0, v0, fmaf(w1, v1, fmaf(w2, v2, fmaf(w3, v3, acc0))));
        acc1 = fmaf(w4, v4, fmaf(w5, v5, fmaf(w6, v6, fmaf(w7, v7, acc1))));
    }
    vals[tid] = (acc0 + acc1) / l;
    __syncthreads();
    if (tid < HID) {
        float mv = (vals[tid] + vals[tid + 64] + vals[tid + 128] + vals[tid + 192]) * 0.25f;
        float mu = wr_sum(mv) * (1.f / HID);
        float dv = mv - mu;
        float var = wr_sum(dv * dv) * (1.f / HID);
        float y = dv * rsqrtf(var + 1e-5f) * g[tid] + b[tid];
        xo[i * HID + tid] = y > 0.f ? y : expm1f(y);
    }
}

// ---------------- fused clause pooling + scorer: out[c] = relu(pm[c]@x2 @Ws+bs)@Wo+bo ----------------
__global__ __launch_bounds__(256) void k_poolscore(const float* __restrict__ pm, const float* __restrict__ x2,
                                                   const float* __restrict__ Ws, const float* __restrict__ bs,
                                                   const float* __restrict__ Wo, const float* __restrict__ bo,
                                                   float* __restrict__ out) {
    int c = blockIdx.x, tid = threadIdx.x;
    int w = tid >> 6, lane = tid & 63;
    __shared__ float sacc[4][HID];
    __shared__ float ce_s[HID];
    float acc = 0.f;
    const float4* pmv = (const float4*)(pm + (size_t)c * N);
#pragma unroll
    for (int it = 0; it < 4; ++it) {
        int vi = w * 256 + it * 64 + lane;   // float4 index into the pm row
        float4 p4 = pmv[vi];
        float pc[4] = {p4.x, p4.y, p4.z, p4.w};
#pragma unroll
        for (int comp = 0; comp < 4; ++comp) {
            unsigned long long msk = __ballot(pc[comp] != 0.f);
            while (msk) {
                int bpos = __ffsll(msk) - 1;
                msk &= msk - 1;
                float pj = __shfl(pc[comp], bpos);
                int j = (w * 256 + it * 64 + bpos) * 4 + comp;
                acc += pj * x2[(size_t)j * HID + lane];
            }
        }
    }
    sacc[w][lane] = acc;
    __syncthreads();
    if (w == 0) {
        ce_s[lane] = sacc[0][lane] + sacc[1][lane] + sacc[2][lane] + sacc[3][lane];
    }
    __syncthreads();
    if (w == 0) {
        float hd = bs[lane];
#pragma unroll 8
        for (int k = 0; k < HID; ++k) hd = fmaf(ce_s[k], Ws[k * HID + lane], hd);
        hd = fmaxf(hd, 0.f);
        float v = wr_sum(hd * Wo[lane]);
        if (lane == 0) out[c] = v + bo[0];
    }
}

extern "C" void kernel_launch(void* const* d_in, const int* in_sizes, int n_in,
                              void* d_out, int out_size, void* d_ws, size_t ws_size,
                              hipStream_t stream) {
    const float* nf  = (const float*)d_in[0];
    const float* adj = (const float*)d_in[1];
    const float* pm  = (const float*)d_in[2];
    const float* W1  = (const float*)d_in[3];
    const float* as1 = (const float*)d_in[4];
    const float* ad1 = (const float*)d_in[5];
    const float* g1  = (const float*)d_in[6];
    const float* b1  = (const float*)d_in[7];
    const float* W2  = (const float*)d_in[8];
    const float* as2 = (const float*)d_in[9];
    const float* ad2 = (const float*)d_in[10];
    const float* g2  = (const float*)d_in[11];
    const float* b2  = (const float*)d_in[12];
    const float* Ws  = (const float*)d_in[13];
    const float* bs  = (const float*)d_in[14];
    const float* Wo  = (const float*)d_in[15];
    const float* bo  = (const float*)d_in[16];
    float* out = (float*)d_out;

    float* p = (float*)d_ws;
    float* h1  = p; p += (size_t)N * F1;
    float* s1  = p; p += (size_t)N * HEADS;
    float* d1  = p; p += (size_t)N * HEADS;
    float* x1  = p; p += (size_t)N * F1;
    float* h2  = p; p += (size_t)N * F1;
    float* s2  = p; p += (size_t)N * HEADS;
    float* d2  = p; p += (size_t)N * HEADS;
    float* x2  = p; p += (size_t)N * HID;
    int* cnt = (int*)p;
    int* idx = cnt + N;

    k_build<<<N, 256, 0, stream>>>(adj, cnt, idx);
    k_gemm1<<<N / R2, 256, 0, stream>>>(nf, W1, as1, ad1, h1, s1, d1);
    k_agg1<<<N, 256, 0, stream>>>(h1, s1, d1, cnt, idx, g1, b1, x1);
    k_gemm2<<<N / R2, 256, 0, stream>>>(x1, W2, as2, ad2, h2, s2, d2);
    k_agg2<<<N, 256, 0, stream>>>(h2, s2, d2, cnt, idx, g2, b2, x2);
    k_poolscore<<<C, 256, 0, stream>>>(pm, x2, Ws, bs, Wo, bo, out);
}